// Round 3
// baseline (5212.994 us; speedup 1.0000x reference)
//
#include <hip/hip_runtime.h>
#include <math.h>

namespace {
constexpr int kH    = 256;   // hidden
constexpr int kM    = 32;    // stack value dim
constexpr int kIn   = 131;   // input dim
constexpr int kOut  = 131;   // output dim
constexpr int kB    = 32;    // batch
constexpr int kTenc = 128;   // encoder steps (X[:-1])
constexpr int kT    = 256;   // total sequential steps
constexpr int kCap  = 257;   // stack capacity
constexpr int kG    = 1024;  // 4*H gates
constexpr int kK    = 288;   // H + M combined recurrent input
constexpr int kVs   = 40;    // Vbuf row stride (pad: bank = (8i+m)%32 -> 2-way max)
}

__device__ __forceinline__ float frcp(float x){ return __builtin_amdgcn_rcpf(x); }
__device__ __forceinline__ float sigf(float x){ return frcp(1.0f + __expf(-x)); }
__device__ __forceinline__ float tanhf_fast(float x){
  // tanh(x) = 1 - 2/(exp(2x)+1); saturates correctly via inf/0
  return 1.0f - 2.0f*frcp(__expf(2.0f*x) + 1.0f);
}

template<int PAT>
__device__ __forceinline__ float swz(float x){
  return __int_as_float(__builtin_amdgcn_ds_swizzle(__float_as_int(x), PAT));
}

__device__ __forceinline__ float4 fma4(float4 a, float s, float4 c){
  c.x += a.x*s; c.y += a.y*s; c.z += a.z*s; c.w += a.w*s; return c;
}

// dst[c*R + r] = src[r*stride + col0 + c]   (dst layout [C][R])
__global__ void k_transpose(float* __restrict__ dst, const float* __restrict__ src,
                            int R, int C, int stride, int col0){
  int idx = blockIdx.x*256 + threadIdx.x;
  if (idx >= R*C) return;
  int rr = idx / C;
  int cc = idx - rr*C;
  dst[cc*R + rr] = src[rr*stride + col0 + cc];
}

// Wp[((k4*256 + j)*4 + jj)*4 + g] = Wcomb[g*256+j][k],  k = k4*4+jj
// Wcomb[col][k] = k<256 ? Whh[col][k] : Wih[col][131 + (k-256)]
__global__ void k_pack(float* __restrict__ dst, const float* __restrict__ Wih,
                       const float* __restrict__ Whh){
  int idx = blockIdx.x*256 + threadIdx.x;
  if (idx >= kK*kG) return;
  int k = idx >> 10;
  int p = idx & 1023;
  int j = p >> 2, g = p & 3;
  int col = g*256 + j;
  float w = (k < kH) ? Whh[col*kH + k] : Wih[col*(kIn+kM) + kIn + (k - kH)];
  int k4 = k >> 2, jj = k & 3;
  dst[(((size_t)k4*256 + j)*4 + jj)*4 + g] = w;
}

// gatesXp[t][b][j][g] = sum_k x_t[b][k]*Wih[g*256+j][k] + bih + bhh
__global__ void k_gatesx(const float* __restrict__ X, const float* __restrict__ Y,
                         const float* __restrict__ WixT_e, const float* __restrict__ WixT_d,
                         const float* __restrict__ bih_e, const float* __restrict__ bhh_e,
                         const float* __restrict__ bih_d, const float* __restrict__ bhh_d,
                         float* __restrict__ gatesXp){
  const int t   = blockIdx.x;                    // 0..255
  const int col = blockIdx.y*256 + threadIdx.x;  // 0..1023 (= g*256 + j)
  __shared__ float xl[kB*kIn];
  const float* xsrc;
  if (t < kTenc)       xsrc = X + (size_t)t*kB*kIn;
  else if (t == kTenc) xsrc = X + (size_t)kTenc*kB*kIn;
  else                 xsrc = Y + (size_t)(t-kTenc-1)*kB*kIn;
  for (int i = threadIdx.x; i < kB*kIn; i += 256) xl[i] = xsrc[i];
  __syncthreads();
  const float* WT   = (t < kTenc) ? WixT_e : WixT_d;
  const float  bias = (t < kTenc) ? (bih_e[col] + bhh_e[col]) : (bih_d[col] + bhh_d[col]);
  float acc[kB];
#pragma unroll
  for (int b = 0; b < kB; ++b) acc[b] = bias;
  for (int k = 0; k < kIn; ++k){
    float wk = WT[k*kG + col];
#pragma unroll
    for (int b = 0; b < kB; ++b) acc[b] += wk * xl[b*kIn + k];
  }
  const int j = col & 255, g = col >> 8;
#pragma unroll
  for (int b = 0; b < kB; ++b)
    gatesXp[(((size_t)t*kB + b)*256 + j)*4 + g] = acc[b];
}

// inclusive suffix sum across a 64-lane wave: result[l] = sum_{l' >= l} x[l']
__device__ __forceinline__ float wave_suffix_incl(float x, int lane){
#pragma unroll
  for (int off = 1; off < 64; off <<= 1){
    float t = __shfl_down(x, off);
    if (lane + off < 64) x += t;
  }
  return x;
}

__global__ void __launch_bounds__(1024)
k_seq(const float* __restrict__ gatesXp,
      const float* __restrict__ Wp_e, const float* __restrict__ Wp_d,
      const float* __restrict__ Wd, const float* __restrict__ bd,
      const float* __restrict__ Wu, const float* __restrict__ bu,
      const float* __restrict__ Wv, const float* __restrict__ bv,
      const float* __restrict__ h0, const float* __restrict__ c0,
      float* __restrict__ Hdec){
  const int b    = blockIdx.x;
  const int tid  = threadIdx.x;
  const int lane = tid & 63;
  const int wave = tid >> 6;
  const int q    = tid >> 8;     // k-quarter 0..3
  const int j    = tid & 255;    // hidden unit / gate-column group

  __shared__ __align__(16) float z[kK];        // [h(256) | r(32)]
  __shared__ float cst[kH];
  __shared__ __align__(16) float red[4*kG];    // [q][j*4+g]
  __shared__ float Vbuf[kCap*kVs];
  __shared__ float sbuf[kCap];
  __shared__ float coeff[kCap];

  if (tid < kH){ z[tid] = h0[tid]; cst[tid] = c0[tid]; }
  if (tid >= kH && tid < kK) z[tid] = 0.f;
  for (int i = tid; i < kCap; i += 1024) sbuf[i] = 0.f;
  for (int i = tid; i < kCap*kVs; i += 1024) Vbuf[i] = 0.f;
  __syncthreads();

  for (int t = 0; t < kT; ++t){
    const float* Wp = (t < kTenc) ? Wp_e : Wp_d;

    // prefetch the x-part gates for phase 2 (threads 0..255)
    float4 gx = {0.f,0.f,0.f,0.f};
    if (tid < kH) gx = *(const float4*)(gatesXp + (((size_t)t*kB + b)*256 + j)*4);

    // ---- phase 1: partial gates for my quarter of K, 4 gate-cols (i,f,g,o of unit j)
    {
      const float4* wp = (const float4*)Wp + ((size_t)(18*q)*256 + j)*4;
      const float4* zp = (const float4*)(z + q*72);
      float4 w0 = wp[0], w1 = wp[1], w2 = wp[2], w3 = wp[3];
      float4 zv = zp[0];
      float4 acc = {0.f,0.f,0.f,0.f};
      for (int c = 0; c < 17; ++c){
        const float4* wn = wp + 1024;           // next chunk (16KB stride)
        float4 n0 = wn[0], n1 = wn[1], n2 = wn[2], n3 = wn[3];
        float4 zn = zp[c+1];
        acc = fma4(w0, zv.x, acc); acc = fma4(w1, zv.y, acc);
        acc = fma4(w2, zv.z, acc); acc = fma4(w3, zv.w, acc);
        w0 = n0; w1 = n1; w2 = n2; w3 = n3; zv = zn; wp = wn;
      }
      acc = fma4(w0, zv.x, acc); acc = fma4(w1, zv.y, acc);
      acc = fma4(w2, zv.z, acc); acc = fma4(w3, zv.w, acc);
      *(float4*)&red[(q << 10) + (j << 2)] = acc;
    }
    __syncthreads();                            // A: red ready

    // ---- phase 2: LSTM cell (threads 0..255), write h into z[0..255]
    if (tid < kH){
      float4 s0 = *(const float4*)&red[0*kG + (j << 2)];
      float4 s1 = *(const float4*)&red[1*kG + (j << 2)];
      float4 s2 = *(const float4*)&red[2*kG + (j << 2)];
      float4 s3 = *(const float4*)&red[3*kG + (j << 2)];
      float gi = gx.x + s0.x + s1.x + s2.x + s3.x;
      float gf = gx.y + s0.y + s1.y + s2.y + s3.y;
      float gg = gx.z + s0.z + s1.z + s2.z + s3.z;
      float go = gx.w + s0.w + s1.w + s2.w + s3.w;
      float ig = sigf(gi), fg = sigf(gf), g2 = tanhf_fast(gg), og = sigf(go);
      float cn = fg*cst[j] + ig*g2;
      cst[j] = cn;
      float hn = og*tanhf_fast(cn);
      z[j] = hn;
      if (t >= kTenc) Hdec[(((size_t)(t - kTenc))*kB + b)*kH + j] = hn;
    }
    __syncthreads();                            // B: h ready

    // ---- phase 3+4: controller + stack (wave0: d,u + scan; waves 4-7: v -> Vbuf[cnt])
    const int cnt = t + 1;
    if (wave == 0){
      // d on lanes 0..31, u on lanes 32..63 (same code path)
      const float* Wdu = (lane < 32) ? Wd : Wu;
      const int kl = lane & 31;
      float p = 0.f;
#pragma unroll
      for (int s = 0; s < 8; ++s) p += z[kl + 32*s] * Wdu[kl + 32*s];
      // butterfly all-reduce within each 32-lane half
      p += swz<0x401F>(p); p += swz<0x201F>(p); p += swz<0x101F>(p);
      p += swz<0x081F>(p); p += swz<0x041F>(p);
      float o  = __shfl_xor(p, 32);
      float dd = sigf(((lane < 32) ? p : o) + bd[0]);
      float uu = sigf(((lane < 32) ? o : p) + bu[0]);

      float sm[5], sn[5];
      float csum = 0.f;
#pragma unroll
      for (int qq = 0; qq < 5; ++qq){
        int i = lane*5 + qq;
        float s = (i < cnt) ? sbuf[i] : 0.f;
        sm[qq] = s; csum += s;
      }
      float run = wave_suffix_incl(csum, lane) - csum;   // strengths above my chunk
      float csum2 = 0.f;
#pragma unroll
      for (int qq = 4; qq >= 0; --qq){
        int i = lane*5 + qq;
        float s;
        if (i == cnt)      s = dd;
        else if (i < cnt)  s = fmaxf(sm[qq] - fmaxf(uu - run, 0.f), 0.f);
        else               s = 0.f;
        sn[qq] = s;
        run  += sm[qq];
        csum2 += s;
      }
#pragma unroll
      for (int qq = 0; qq < 5; ++qq){
        int i = lane*5 + qq;
        if (i < kCap) sbuf[i] = sn[qq];
      }
      float run2 = wave_suffix_incl(csum2, lane) - csum2;
#pragma unroll
      for (int qq = 4; qq >= 0; --qq){
        int i = lane*5 + qq;
        float cf = fminf(sn[qq], fmaxf(1.f - run2, 0.f));
        if (i < kCap) coeff[i] = cf;
        run2 += sn[qq];
      }
    } else if (tid >= 256 && tid < 512){
      const int m = (tid - 256) >> 3, l = tid & 7;
      float p = 0.f;
      for (int k2 = l; k2 < kH; k2 += 8) p += z[k2] * Wv[m*kH + k2];
      p += swz<0x101F>(p); p += swz<0x081F>(p); p += swz<0x041F>(p);
      if (l == 0) Vbuf[cnt*kVs + m] = tanhf_fast(p + bv[m]);
    }
    __syncthreads();                            // D: coeff + Vbuf[cnt] ready

    // ---- phase 5: r[m] = sum_i coeff[i]*Vbuf[i][m]  (threads 0..255, 8 lanes per m)
    if (tid < kH){
      const int m = tid >> 3, l = tid & 7;
      float p = 0.f;
      for (int i = l; i <= cnt; i += 8) p += coeff[i]*Vbuf[i*kVs + m];
      p += swz<0x101F>(p); p += swz<0x081F>(p); p += swz<0x041F>(p);
      if (l == 0) z[kH + m] = p;
    }
    __syncthreads();                            // E: r (z tail) ready for next step
  }
}

// oc = tanh(h@Wo^T + bo); out = log_softmax(oc@Wlin^T + blin)
__global__ void k_out(const float* __restrict__ Hdec,
                      const float* __restrict__ WoT, const float* __restrict__ bo,
                      const float* __restrict__ WlinT, const float* __restrict__ blin,
                      float* __restrict__ out){
  const int row = blockIdx.x;    // t*32 + b
  const int tid = threadIdx.x;   // 256
  __shared__ float hr[kH], oc[kH], lg[kOut], st[2];
  hr[tid] = Hdec[(size_t)row*kH + tid];
  __syncthreads();
  float a = bo[tid];
  for (int k = 0; k < kH; ++k) a += hr[k]*WoT[k*kH + tid];
  oc[tid] = tanhf(a);
  __syncthreads();
  if (tid < kOut){
    float a2 = blin[tid];
    for (int k = 0; k < kH; ++k) a2 += oc[k]*WlinT[k*kOut + tid];
    lg[tid] = a2;
  }
  __syncthreads();
  if (tid < 64){
    float mx = -3.4e38f;
    for (int i = tid; i < kOut; i += 64) mx = fmaxf(mx, lg[i]);
#pragma unroll
    for (int off = 32; off; off >>= 1) mx = fmaxf(mx, __shfl_down(mx, off));
    mx = __shfl(mx, 0);
    float se = 0.f;
    for (int i = tid; i < kOut; i += 64) se += expf(lg[i] - mx);
#pragma unroll
    for (int off = 32; off; off >>= 1) se += __shfl_down(se, off);
    if (tid == 0){ st[0] = mx; st[1] = logf(se); }
  }
  __syncthreads();
  if (tid < kOut) out[(size_t)row*kOut + tid] = lg[tid] - st[0] - st[1];
}

extern "C" void kernel_launch(void* const* d_in, const int* in_sizes, int n_in,
                              void* d_out, int out_size, void* d_ws, size_t ws_size,
                              hipStream_t stream){
  (void)in_sizes; (void)n_in; (void)out_size; (void)ws_size;
  const float* X     = (const float*)d_in[0];
  const float* Y     = (const float*)d_in[1];
  const float* Wih_e = (const float*)d_in[2];
  const float* Whh_e = (const float*)d_in[3];
  const float* bih_e = (const float*)d_in[4];
  const float* bhh_e = (const float*)d_in[5];
  const float* Wih_d = (const float*)d_in[6];
  const float* Whh_d = (const float*)d_in[7];
  const float* bih_d = (const float*)d_in[8];
  const float* bhh_d = (const float*)d_in[9];
  const float* Wd    = (const float*)d_in[10];
  const float* bd    = (const float*)d_in[11];
  const float* Wu    = (const float*)d_in[12];
  const float* bu    = (const float*)d_in[13];
  const float* Wv    = (const float*)d_in[14];
  const float* bv    = (const float*)d_in[15];
  const float* Wo    = (const float*)d_in[16];
  const float* bo    = (const float*)d_in[17];
  const float* Wlin  = (const float*)d_in[18];
  const float* blin  = (const float*)d_in[19];
  const float* h0    = (const float*)d_in[20];
  const float* c0    = (const float*)d_in[21];
  float* out = (float*)d_out;

  float* ws = (float*)d_ws;
  size_t o = 0;
  float* gatesXp = ws + o; o += (size_t)kT*kB*kG;   // 8,388,608
  float* Wp_e    = ws + o; o += (size_t)kK*kG;      // 294,912
  float* Wp_d    = ws + o; o += (size_t)kK*kG;
  float* WixT_e  = ws + o; o += (size_t)kIn*kG;     // 134,144
  float* WixT_d  = ws + o; o += (size_t)kIn*kG;
  float* WoT     = ws + o; o += (size_t)kH*kH;
  float* WlinT   = ws + o; o += (size_t)kH*kOut;
  float* Hdec    = ws + o; o += (size_t)128*kB*kH;

  auto tr = [&](float* dst, const float* src, int R, int C, int stride, int col0){
    int n = R*C;
    k_transpose<<<(n+255)/256, 256, 0, stream>>>(dst, src, R, C, stride, col0);
  };
  tr(WixT_e, Wih_e, kG, kIn, kIn+kM, 0);
  tr(WixT_d, Wih_d, kG, kIn, kIn+kM, 0);
  tr(WoT,   Wo,   kH,  kH, kH, 0);
  tr(WlinT, Wlin, kOut, kH, kH, 0);

  k_pack<<<(kK*kG+255)/256, 256, 0, stream>>>(Wp_e, Wih_e, Whh_e);
  k_pack<<<(kK*kG+255)/256, 256, 0, stream>>>(Wp_d, Wih_d, Whh_d);

  k_gatesx<<<dim3(kT,4), 256, 0, stream>>>(X, Y, WixT_e, WixT_d,
                                           bih_e, bhh_e, bih_d, bhh_d, gatesXp);
  k_seq<<<kB, 1024, 0, stream>>>(gatesXp, Wp_e, Wp_d,
                                 Wd, bd, Wu, bu, Wv, bv, h0, c0, Hdec);
  k_out<<<128*kB, 256, 0, stream>>>(Hdec, WoT, bo, WlinT, blin, out);
}